// Round 10
// baseline (142.204 us; speedup 1.0000x reference)
//
#include <hip/hip_runtime.h>
#include <hip/hip_bf16.h>

// ---------------------------------------------------------------------------
// RnnGruModel: MLP (1600->60->15->10) fused with GRU-layer0 input-gate
// precompute, then 3 stacked GRU layers (H=5) + output projection.
// X@W1^T done in bf16 MFMA with hi/lo split (3 products) -> ~fp32 accuracy.
// GRU: systolic layer pipeline, ONE BATCH PER WAVE, ONE GATE PER LANE.
//   wave = 4 rows of 16 lanes. row r (0..2) = GRU layer r at t = s - r;
//   row 3 = output projection (lane 48). lane g<15 of a layer-row owns gate g.
//   r/z -> n-lane via DPP row_shr; h/x replication via 10 ds_bpermute.
// R10: pack 8 compute waves (8 batches) + 1 producer wave per block
// (576 thr, 16 blocks) so ~2.25 waves/SIMD co-reside -> the per-step
// latency chain (bperm->dot->sigmoid->tanh->bperm, ~500cy solo) overlaps
// across independent batch chains. GSTEP math byte-identical to R9.
// Layouts: X (T,B,F) row-major, row r = t*128 + b.  Output (T,1,B): t*128+b.
// ---------------------------------------------------------------------------

#define T_DIM 256
#define B_DIM 128
#define F_DIM 1600
#define H1_DIM 60
#define H2_DIM 15
#define H3_DIM 10
#define GH 5
#define NSTEP 50          // MLP K-steps of 32 (1600/32)
#define CT 32             // GRU LDS chunk: timesteps per buffer
#define NCH (T_DIM / CT)  // 8 chunks
#define WB 8              // GRU batches (compute waves) per block

#define DPP_SHR5  0x115   // row_shr:5  (lane i <- lane i-5 within 16-lane row)
#define DPP_SHR10 0x11A   // row_shr:10 (lane i <- lane i-10)

typedef __attribute__((ext_vector_type(8))) short bf16x8;   // MFMA A/B frag (4 VGPRs)
typedef __attribute__((ext_vector_type(4))) float f32x4;    // MFMA C/D frag

__device__ __forceinline__ float fast_tanh(float x) {
    float e = __expf(2.0f * x);
    return 1.0f - __fdividef(2.0f, e + 1.0f);   // safe at +-inf
}
__device__ __forceinline__ float fast_sigmoid(float x) {
    return __fdividef(1.0f, 1.0f + __expf(-x)); // safe at +-inf
}
__device__ __forceinline__ ushort f2bf_rn(float x) {        // round-to-nearest bf16
    uint u = __float_as_uint(x);
    u += 0x7fffu + ((u >> 16) & 1u);
    return (ushort)(u >> 16);
}
template <int CTRL>
__device__ __forceinline__ float dppf(float v) {
    return __int_as_float(
        __builtin_amdgcn_mov_dpp(__float_as_int(v), CTRL, 0xf, 0xf, true));
}
__device__ __forceinline__ float bperm(int addr, float v) {
    return __int_as_float(__builtin_amdgcn_ds_bpermute(addr, __float_as_int(v)));
}

// ---------------------------------------------------------------------------
// Kernel 0: pack W1 (60x1600 fp32, zero-padded to 64 rows) into frag-ordered
// bf16 hi/lo pairs (unchanged, verified).
// ---------------------------------------------------------------------------
__global__ __launch_bounds__(256) void pack_w1_kernel(
    const float* __restrict__ W1, ushort* __restrict__ Wp)
{
    const int s  = blockIdx.x;       // 0..49
    const int t  = threadIdx.x;
    const int nf = t >> 6;
    const int l  = t & 63;
    const int n  = nf * 16 + (l & 15);
    const int g  = l >> 4;

    ushort hi[8], lo[8];
#pragma unroll
    for (int j = 0; j < 8; ++j) {
        const int k = s * 32 + g * 8 + j;
        const float v = (n < H1_DIM) ? W1[n * F_DIM + k] : 0.0f;
        const ushort h = f2bf_rn(v);
        const float hf = __uint_as_float(((uint)h) << 16);
        const float r  = v - hf;                       // exact
        hi[j] = h;
        lo[j] = (ushort)(__float_as_uint(r) >> 16);    // truncate: |err| ~ 2^-17 |v|
    }
    ushort* dst = Wp + ((size_t)(s * 8 + nf * 2)) * 512 + l * 8;
#pragma unroll
    for (int j = 0; j < 8; ++j) dst[j] = hi[j];
#pragma unroll
    for (int j = 0; j < 8; ++j) dst[512 + j] = lo[j];
}

// ---------------------------------------------------------------------------
// Kernel 1: per-row MLP + gi0 precompute, MFMA edition (unchanged, verified).
// ---------------------------------------------------------------------------
__global__ __launch_bounds__(256) void mlp_kernel(
    const float* __restrict__ X,
    const ushort* __restrict__ Wp,
    const float* __restrict__ b1,
    const float* __restrict__ W2, const float* __restrict__ b2,
    const float* __restrict__ W3, const float* __restrict__ b3,
    const float* __restrict__ wih0, const float* __restrict__ bih0,
    float* __restrict__ gi0)
{
    __shared__ float red[4 * 4096];   // 64 KB: per-wave 64x64 C partials

    const int tid  = threadIdx.x;
    const int l    = tid & 63;
    const int w    = __builtin_amdgcn_readfirstlane(tid >> 6);
    const int lm   = l & 15;          // A-row / B-col lane index
    const int g    = l >> 4;          // k-slot group
    const int row0 = blockIdx.x * 64;

    f32x4 acc[4][4];
#pragma unroll
    for (int mf = 0; mf < 4; ++mf)
#pragma unroll
        for (int nf = 0; nf < 4; ++nf)
            acc[mf][nf] = (f32x4){0.f, 0.f, 0.f, 0.f};

    const int s0 = (w * NSTEP) >> 2;        // 0,12,25,37
    const int s1 = ((w + 1) * NSTEP) >> 2;  // 12,25,37,50

    for (int s = s0; s < s1; ++s) {
        bf16x8 bh[4], bl[4];
        const ushort* wp_s = Wp + (size_t)s * 4096 + l * 8;
#pragma unroll
        for (int nf = 0; nf < 4; ++nf) {
            bh[nf] = *(const bf16x8*)(wp_s + (nf * 2 + 0) * 512);
            bl[nf] = *(const bf16x8*)(wp_s + (nf * 2 + 1) * 512);
        }
        bf16x8 a_hi[4], a_lo[4];
#pragma unroll
        for (int mf = 0; mf < 4; ++mf) {
            const float* ap = X + (size_t)(row0 + mf * 16 + lm) * F_DIM + s * 32 + g * 8;
            const float4 x0 = *(const float4*)ap;
            const float4 x1 = *(const float4*)(ap + 4);
            const float xs8[8] = {x0.x, x0.y, x0.z, x0.w, x1.x, x1.y, x1.z, x1.w};
            bf16x8 ah, al;
#pragma unroll
            for (int j = 0; j < 8; ++j) {
                const float v = xs8[j];
                const uint  u = __float_as_uint(v);
                const uint uh = (u + 0x7fffu + ((u >> 16) & 1u)) & 0xffff0000u;
                const float hf = __uint_as_float(uh);
                const float r  = v - hf;               // exact
                ah[j] = (short)(uh >> 16);
                al[j] = (short)(__float_as_uint(r) >> 16);
            }
            a_hi[mf] = ah; a_lo[mf] = al;
        }
#pragma unroll
        for (int mf = 0; mf < 4; ++mf)
#pragma unroll
            for (int nf = 0; nf < 4; ++nf) {
                f32x4 c = acc[mf][nf];
                c = __builtin_amdgcn_mfma_f32_16x16x32_bf16(a_lo[mf], bh[nf], c, 0, 0, 0);
                c = __builtin_amdgcn_mfma_f32_16x16x32_bf16(a_hi[mf], bl[nf], c, 0, 0, 0);
                c = __builtin_amdgcn_mfma_f32_16x16x32_bf16(a_hi[mf], bh[nf], c, 0, 0, 0);
                acc[mf][nf] = c;
            }
    }

    float* myred = red + w * 4096;
#pragma unroll
    for (int mf = 0; mf < 4; ++mf)
#pragma unroll
        for (int nf = 0; nf < 4; ++nf)
#pragma unroll
            for (int q = 0; q < 4; ++q)
                myred[(mf * 16 + g * 4 + q) * 64 + nf * 16 + lm] = acc[mf][nf][q];
    __syncthreads();

    float rsum[16];
#pragma unroll
    for (int i = 0; i < 16; ++i) {
        const int p = tid + 256 * i;
        rsum[i] = red[p] + red[4096 + p] + red[8192 + p] + red[12288 + p];
    }
    __syncthreads();
    float* redp = red + 8192;              // 64 x 65 padded
#pragma unroll
    for (int i = 0; i < 16; ++i) {
        const int p = tid + 256 * i;
        redp[(p >> 6) * 65 + (p & 63)] = rsum[i];
    }
    __syncthreads();
    if (w != 0) return;

    float h1v[H1_DIM];
#pragma unroll
    for (int o = 0; o < H1_DIM; ++o)
        h1v[o] = fast_tanh(redp[l * 65 + o] + b1[o]);

    float h2v[H2_DIM];
#pragma unroll
    for (int j = 0; j < H2_DIM; ++j) {
        float sacc = b2[j];
#pragma unroll
        for (int o = 0; o < H1_DIM; ++o) sacc += W2[j * H1_DIM + o] * h1v[o];
        h2v[j] = fast_tanh(sacc);
    }

    float h3v[H3_DIM];
#pragma unroll
    for (int m = 0; m < H3_DIM; ++m) {
        float sacc = b3[m];
#pragma unroll
        for (int j = 0; j < H2_DIM; ++j) sacc += W3[m * H2_DIM + j] * h2v[j];
        h3v[m] = sacc;
    }

    float gv[15];
#pragma unroll
    for (int q = 0; q < 15; ++q) {
        float sacc = bih0[q];
#pragma unroll
        for (int m = 0; m < H3_DIM; ++m) sacc += wih0[q * H3_DIM + m] * h3v[m];
        gv[q] = sacc;
    }

    const int row = row0 + l;
    float4* dst = (float4*)(gi0 + (size_t)row * 16);
    dst[0] = make_float4(gv[0],  gv[1],  gv[2],  gv[3]);
    dst[1] = make_float4(gv[4],  gv[5],  gv[6],  gv[7]);
    dst[2] = make_float4(gv[8],  gv[9],  gv[10], gv[11]);
    dst[3] = make_float4(gv[12], gv[13], gv[14], 0.0f);
}

// ---------------------------------------------------------------------------
// Kernel 2: systolic GRU, one batch per wave, one gate per lane.
// Grid: 16 blocks x 576 threads. Waves 0..7 = compute (batches b0..b0+7);
// wave 8 = producer staging all 8 batches' gi0 chunks (CT=32, double buf).
// ~2.25 waves/SIMD co-resident -> latency chains overlap across batches.
// ---------------------------------------------------------------------------

// producer: stage chunk C into gbuf[C&1]; 1024 float4 per chunk, 16 per lane
#define STAGE(C) do {                                                       \
    const int _cb = (C) & 1;                                                \
    float4 _v[16];                                                          \
    _Pragma("unroll") for (int _i = 0; _i < 16; ++_i) {                     \
        const int _f = lane + 64 * _i;                                      \
        const int _t = _f >> 5, _bb = (_f >> 2) & 7, _q = _f & 3;           \
        _v[_i] = *(const float4*)(gi0 +                                     \
            ((size_t)(((C) * CT + _t) * B_DIM + b0 + _bb)) * 16 + _q * 4);  \
    }                                                                       \
    _Pragma("unroll") for (int _i = 0; _i < 16; ++_i) {                     \
        const int _f = lane + 64 * _i;                                      \
        const int _t = _f >> 5, _bb = (_f >> 2) & 7, _q = _f & 3;           \
        *(float4*)&gbuf[_cb][_t][_bb][_q * 4] = _v[_i];                     \
    }                                                                       \
} while (0)

#define PREF(CB, TL) do {                                                   \
    pre = lptr[(CB) * (CT * WB * 16) + (TL) * (WB * 16)];                   \
} while (0)

#define GSTEP(S, PREFCODE) do {                                             \
    /* dots: aA = bA(+gi) + wi.x ; aB = bB + wh.h  (ref-exact order) */     \
    float aA = bA + pre;                                                    \
    _Pragma("unroll") for (int _j = 0; _j < GH; ++_j)                       \
        aA = fmaf(wi[_j], xn[_j], aA);                                      \
    float aB = fmaf(wh[0], hn[0], bB);                                      \
    _Pragma("unroll") for (int _j = 1; _j < GH; ++_j)                       \
        aB = fmaf(wh[_j], hn[_j], aB);                                      \
    PREFCODE                                                                \
    const float sAv = aA + aB;                                              \
    const float sg  = fast_sigmoid(sAv);                                    \
    const float rn  = dppf<DPP_SHR10>(sg);   /* r_i -> n-lane (g-10) */     \
    const float zn  = dppf<DPP_SHR5>(sg);    /* z_i -> n-lane (g-5)  */     \
    if (lane == 48 && (unsigned)((S) - 3) < (unsigned)T_DIM)                \
        out[((S) - 3) * B_DIM + b] = sAv;    /* projection pre-activation */\
    const float nv = fast_tanh(fmaf(rn, aB, aA));                           \
    const float hu = fmaf(zn, hm - nv, nv);                                 \
    const bool _valid = (unsigned)((S) - row) < (unsigned)T_DIM;            \
    hm = _valid ? hu : hm;                                                  \
    /* replicate h (own row) and x (prev row) for next step */              \
    _Pragma("unroll") for (int _j = 0; _j < GH; ++_j) {                     \
        hn[_j] = bperm(a_self[_j], hm);                                     \
        xn[_j] = bperm(a_prev[_j], hm);                                     \
    }                                                                       \
} while (0)

__global__ __launch_bounds__(576, 1) void gru_kernel(
    const float* __restrict__ gi0,
    const float* __restrict__ whh0, const float* __restrict__ bhh0,
    const float* __restrict__ wih1, const float* __restrict__ whh1,
    const float* __restrict__ bih1, const float* __restrict__ bhh1,
    const float* __restrict__ wih2, const float* __restrict__ whh2,
    const float* __restrict__ bih2, const float* __restrict__ bhh2,
    const float* __restrict__ Wout, const float* __restrict__ bout,
    float* __restrict__ out)
{
    __shared__ float gbuf[2][CT][WB][16];  // 32 KB double-buffered gi0 chunks

    const int tid  = threadIdx.x;
    const int w    = __builtin_amdgcn_readfirstlane(tid >> 6);
    const int lane = tid & 63;
    const int b0   = blockIdx.x * WB;

    if (w == WB) {
        // ---------------- producer wave ----------------
        STAGE(0);
        __syncthreads();                   // chunk 0 visible
        for (int c = 0; c < NCH; ++c) {
            if (c + 1 < NCH) STAGE(c + 1);
            __syncthreads();               // publish chunk c+1; consumer done with c
        }
        return;
    }

    // ---------------- consumer waves (one batch each) ----------------
    const int row = lane >> 4;             // 0..2 = layer, 3 = projection
    const int g   = lane & 15;             // gate (r:0-4, z:5-9, n:10-14)
    const int b   = b0 + w;                // this wave's batch

    // ---- per-lane weights: ONE gate row ----
    float wi[GH], wh[GH];
    float bA = 0.f, bB = 0.f;
#pragma unroll
    for (int j = 0; j < GH; ++j) { wi[j] = 0.f; wh[j] = 0.f; }

    if (row == 0) {
        if (g < 15) {                      // L0: x-side is in gi0 (incl. bih0)
#pragma unroll
            for (int j = 0; j < GH; ++j) wh[j] = whh0[g * GH + j];
            bB = bhh0[g];
        }
    } else if (row < 3) {
        const float* wip = (row == 1) ? wih1 : wih2;
        const float* whp = (row == 1) ? whh1 : whh2;
        const float* bip = (row == 1) ? bih1 : bih2;
        const float* bhp = (row == 1) ? bhh1 : bhh2;
        if (g < 15) {
#pragma unroll
            for (int j = 0; j < GH; ++j) {
                wi[j] = wip[g * GH + j];
                wh[j] = whp[g * GH + j];
            }
            bA = bip[g];
            bB = bhp[g];
        }
    } else if (g == 0) {                   // projection: y = Wout.h2 + bout
#pragma unroll
        for (int j = 0; j < GH; ++j) wi[j] = Wout[j];
        bA = bout[0];
    }

    // ---- bpermute addresses (constant): n-lanes of own / previous row ----
    int a_self[GH], a_prev[GH];
    const int sbase = row * 16;
    const int pbase = ((row + 3) & 3) * 16;    // row-1 mod 4 (row0 wraps; x*0)
#pragma unroll
    for (int j = 0; j < GH; ++j) {
        a_self[j] = (sbase + 10 + j) << 2;
        a_prev[j] = (pbase + 10 + j) << 2;
    }

    // ---- pre (gi0) LDS column: row0 lane g -> col g; others -> col 15 (=0)
    const float* lptr = &gbuf[0][0][w][(row == 0) ? g : 15];

    float hn[GH] = {0.f, 0.f, 0.f, 0.f, 0.f};
    float xn[GH] = {0.f, 0.f, 0.f, 0.f, 0.f};
    float hm = 0.f, pre = 0.f;

    __syncthreads();                       // chunk 0 staged
    PREF(0, 0);

    for (int c = 0; c < NCH; ++c) {
        const int cb = c & 1;
#pragma unroll 2
        for (int tl = 0; tl < CT; ++tl) {
            const int s = c * CT + tl;
            GSTEP(s, if (tl + 1 < CT) { PREF(cb, tl + 1); });
        }
        __syncthreads();                   // chunk c done; chunk c+1 published
        if (c + 1 < NCH) { PREF((c + 1) & 1, 0); }
    }

    // drain: 3 wall steps flush the layer pipeline (pre stale but h masked)
    for (int s = T_DIM; s < T_DIM + 3; ++s) {
        GSTEP(s, ;);
    }
}

// ---------------------------------------------------------------------------
extern "C" void kernel_launch(void* const* d_in, const int* in_sizes, int n_in,
                              void* d_out, int out_size, void* d_ws, size_t ws_size,
                              hipStream_t stream)
{
    (void)in_sizes; (void)n_in; (void)out_size; (void)ws_size;

    const float* X    = (const float*)d_in[0];
    const float* W1   = (const float*)d_in[1];
    const float* b1   = (const float*)d_in[2];
    const float* W2   = (const float*)d_in[3];
    const float* b2   = (const float*)d_in[4];
    const float* W3   = (const float*)d_in[5];
    const float* b3   = (const float*)d_in[6];
    const float* wih0 = (const float*)d_in[7];
    const float* whh0 = (const float*)d_in[8];
    const float* bih0 = (const float*)d_in[9];
    const float* bhh0 = (const float*)d_in[10];
    const float* wih1 = (const float*)d_in[11];
    const float* whh1 = (const float*)d_in[12];
    const float* bih1 = (const float*)d_in[13];
    const float* bhh1 = (const float*)d_in[14];
    const float* wih2 = (const float*)d_in[15];
    const float* whh2 = (const float*)d_in[16];
    const float* bih2 = (const float*)d_in[17];
    const float* bhh2 = (const float*)d_in[18];
    const float* Wout = (const float*)d_in[19];
    const float* bout = (const float*)d_in[20];

    ushort* Wp  = (ushort*)d_ws;                       // 400 frags * 1 KB = 400 KB
    float*  gi0 = (float*)((char*)d_ws + 524288);      // (32768, 16) fp32 = 2 MB

    pack_w1_kernel<<<NSTEP, 256, 0, stream>>>(W1, Wp);
    mlp_kernel<<<512, 256, 0, stream>>>(X, Wp, b1, W2, b2, W3, b3, wih0, bih0, gi0);
    gru_kernel<<<16, 576, 0, stream>>>(gi0, whh0, bhh0,
                                       wih1, whh1, bih1, bhh1,
                                       wih2, whh2, bih2, bhh2,
                                       Wout, bout, (float*)d_out);
}

// Round 11
// 133.860 us; speedup vs baseline: 1.0623x; 1.0623x over previous
//
#include <hip/hip_runtime.h>
#include <hip/hip_bf16.h>

// ---------------------------------------------------------------------------
// RnnGruModel: MLP (1600->60->15->10) fused with GRU-layer0 input-gate
// precompute, then 3 stacked GRU layers (H=5) + output projection.
// X@W1^T done in bf16 MFMA with hi/lo split (3 products) -> ~fp32 accuracy.
// GRU: systolic layer pipeline, ONE BATCH PER WAVE, ONE GATE PER LANE
// (R9 grid: 128 blocks, wave0 compute + wave1 producer).
// R11: h-broadcast via v_readlane -> wave-uniform SGPRs (VALU domain) instead
// of ds_bpermute (DS pipe, ~120cy on the recurrence chain). Every lane
// computes tree-dots against all 3 layer h-vectors (SGPR operand fmas) and
// selects its row's result -- +40 issued insts, -~120cy chain latency.
// Layouts: X (T,B,F) row-major, row r = t*128 + b.  Output (T,1,B): t*128+b.
// ---------------------------------------------------------------------------

#define T_DIM 256
#define B_DIM 128
#define F_DIM 1600
#define H1_DIM 60
#define H2_DIM 15
#define H3_DIM 10
#define GH 5
#define NSTEP 50          // MLP K-steps of 32 (1600/32)
#define CT 32             // GRU LDS chunk: timesteps per buffer
#define NCH (T_DIM / CT)  // 8 chunks

#define DPP_SHR5  0x115   // row_shr:5  (lane i <- lane i-5 within 16-lane row)
#define DPP_SHR10 0x11A   // row_shr:10 (lane i <- lane i-10)

typedef __attribute__((ext_vector_type(8))) short bf16x8;   // MFMA A/B frag (4 VGPRs)
typedef __attribute__((ext_vector_type(4))) float f32x4;    // MFMA C/D frag

__device__ __forceinline__ float fast_tanh(float x) {
    float e = __expf(2.0f * x);
    return 1.0f - __fdividef(2.0f, e + 1.0f);   // safe at +-inf
}
__device__ __forceinline__ float fast_sigmoid(float x) {
    return __fdividef(1.0f, 1.0f + __expf(-x)); // safe at +-inf
}
__device__ __forceinline__ ushort f2bf_rn(float x) {        // round-to-nearest bf16
    uint u = __float_as_uint(x);
    u += 0x7fffu + ((u >> 16) & 1u);
    return (ushort)(u >> 16);
}
template <int CTRL>
__device__ __forceinline__ float dppf(float v) {
    return __int_as_float(
        __builtin_amdgcn_mov_dpp(__float_as_int(v), CTRL, 0xf, 0xf, true));
}
__device__ __forceinline__ float rlane(float v, int l) {
    return __int_as_float(__builtin_amdgcn_readlane(__float_as_int(v), l));
}

// ---------------------------------------------------------------------------
// Kernel 0: pack W1 (60x1600 fp32, zero-padded to 64 rows) into frag-ordered
// bf16 hi/lo pairs (unchanged, verified).
// ---------------------------------------------------------------------------
__global__ __launch_bounds__(256) void pack_w1_kernel(
    const float* __restrict__ W1, ushort* __restrict__ Wp)
{
    const int s  = blockIdx.x;       // 0..49
    const int t  = threadIdx.x;
    const int nf = t >> 6;
    const int l  = t & 63;
    const int n  = nf * 16 + (l & 15);
    const int g  = l >> 4;

    ushort hi[8], lo[8];
#pragma unroll
    for (int j = 0; j < 8; ++j) {
        const int k = s * 32 + g * 8 + j;
        const float v = (n < H1_DIM) ? W1[n * F_DIM + k] : 0.0f;
        const ushort h = f2bf_rn(v);
        const float hf = __uint_as_float(((uint)h) << 16);
        const float r  = v - hf;                       // exact
        hi[j] = h;
        lo[j] = (ushort)(__float_as_uint(r) >> 16);    // truncate: |err| ~ 2^-17 |v|
    }
    ushort* dst = Wp + ((size_t)(s * 8 + nf * 2)) * 512 + l * 8;
#pragma unroll
    for (int j = 0; j < 8; ++j) dst[j] = hi[j];
#pragma unroll
    for (int j = 0; j < 8; ++j) dst[512 + j] = lo[j];
}

// ---------------------------------------------------------------------------
// Kernel 1: per-row MLP + gi0 precompute, MFMA edition (unchanged, verified).
// ---------------------------------------------------------------------------
__global__ __launch_bounds__(256) void mlp_kernel(
    const float* __restrict__ X,
    const ushort* __restrict__ Wp,
    const float* __restrict__ b1,
    const float* __restrict__ W2, const float* __restrict__ b2,
    const float* __restrict__ W3, const float* __restrict__ b3,
    const float* __restrict__ wih0, const float* __restrict__ bih0,
    float* __restrict__ gi0)
{
    __shared__ float red[4 * 4096];   // 64 KB: per-wave 64x64 C partials

    const int tid  = threadIdx.x;
    const int l    = tid & 63;
    const int w    = __builtin_amdgcn_readfirstlane(tid >> 6);
    const int lm   = l & 15;          // A-row / B-col lane index
    const int g    = l >> 4;          // k-slot group
    const int row0 = blockIdx.x * 64;

    f32x4 acc[4][4];
#pragma unroll
    for (int mf = 0; mf < 4; ++mf)
#pragma unroll
        for (int nf = 0; nf < 4; ++nf)
            acc[mf][nf] = (f32x4){0.f, 0.f, 0.f, 0.f};

    const int s0 = (w * NSTEP) >> 2;        // 0,12,25,37
    const int s1 = ((w + 1) * NSTEP) >> 2;  // 12,25,37,50

    for (int s = s0; s < s1; ++s) {
        bf16x8 bh[4], bl[4];
        const ushort* wp_s = Wp + (size_t)s * 4096 + l * 8;
#pragma unroll
        for (int nf = 0; nf < 4; ++nf) {
            bh[nf] = *(const bf16x8*)(wp_s + (nf * 2 + 0) * 512);
            bl[nf] = *(const bf16x8*)(wp_s + (nf * 2 + 1) * 512);
        }
        bf16x8 a_hi[4], a_lo[4];
#pragma unroll
        for (int mf = 0; mf < 4; ++mf) {
            const float* ap = X + (size_t)(row0 + mf * 16 + lm) * F_DIM + s * 32 + g * 8;
            const float4 x0 = *(const float4*)ap;
            const float4 x1 = *(const float4*)(ap + 4);
            const float xs8[8] = {x0.x, x0.y, x0.z, x0.w, x1.x, x1.y, x1.z, x1.w};
            bf16x8 ah, al;
#pragma unroll
            for (int j = 0; j < 8; ++j) {
                const float v = xs8[j];
                const uint  u = __float_as_uint(v);
                const uint uh = (u + 0x7fffu + ((u >> 16) & 1u)) & 0xffff0000u;
                const float hf = __uint_as_float(uh);
                const float r  = v - hf;               // exact
                ah[j] = (short)(uh >> 16);
                al[j] = (short)(__float_as_uint(r) >> 16);
            }
            a_hi[mf] = ah; a_lo[mf] = al;
        }
#pragma unroll
        for (int mf = 0; mf < 4; ++mf)
#pragma unroll
            for (int nf = 0; nf < 4; ++nf) {
                f32x4 c = acc[mf][nf];
                c = __builtin_amdgcn_mfma_f32_16x16x32_bf16(a_lo[mf], bh[nf], c, 0, 0, 0);
                c = __builtin_amdgcn_mfma_f32_16x16x32_bf16(a_hi[mf], bl[nf], c, 0, 0, 0);
                c = __builtin_amdgcn_mfma_f32_16x16x32_bf16(a_hi[mf], bh[nf], c, 0, 0, 0);
                acc[mf][nf] = c;
            }
    }

    float* myred = red + w * 4096;
#pragma unroll
    for (int mf = 0; mf < 4; ++mf)
#pragma unroll
        for (int nf = 0; nf < 4; ++nf)
#pragma unroll
            for (int q = 0; q < 4; ++q)
                myred[(mf * 16 + g * 4 + q) * 64 + nf * 16 + lm] = acc[mf][nf][q];
    __syncthreads();

    float rsum[16];
#pragma unroll
    for (int i = 0; i < 16; ++i) {
        const int p = tid + 256 * i;
        rsum[i] = red[p] + red[4096 + p] + red[8192 + p] + red[12288 + p];
    }
    __syncthreads();
    float* redp = red + 8192;              // 64 x 65 padded
#pragma unroll
    for (int i = 0; i < 16; ++i) {
        const int p = tid + 256 * i;
        redp[(p >> 6) * 65 + (p & 63)] = rsum[i];
    }
    __syncthreads();
    if (w != 0) return;

    float h1v[H1_DIM];
#pragma unroll
    for (int o = 0; o < H1_DIM; ++o)
        h1v[o] = fast_tanh(redp[l * 65 + o] + b1[o]);

    float h2v[H2_DIM];
#pragma unroll
    for (int j = 0; j < H2_DIM; ++j) {
        float sacc = b2[j];
#pragma unroll
        for (int o = 0; o < H1_DIM; ++o) sacc += W2[j * H1_DIM + o] * h1v[o];
        h2v[j] = fast_tanh(sacc);
    }

    float h3v[H3_DIM];
#pragma unroll
    for (int m = 0; m < H3_DIM; ++m) {
        float sacc = b3[m];
#pragma unroll
        for (int j = 0; j < H2_DIM; ++j) sacc += W3[m * H2_DIM + j] * h2v[j];
        h3v[m] = sacc;
    }

    float gv[15];
#pragma unroll
    for (int q = 0; q < 15; ++q) {
        float sacc = bih0[q];
#pragma unroll
        for (int m = 0; m < H3_DIM; ++m) sacc += wih0[q * H3_DIM + m] * h3v[m];
        gv[q] = sacc;
    }

    const int row = row0 + l;
    float4* dst = (float4*)(gi0 + (size_t)row * 16);
    dst[0] = make_float4(gv[0],  gv[1],  gv[2],  gv[3]);
    dst[1] = make_float4(gv[4],  gv[5],  gv[6],  gv[7]);
    dst[2] = make_float4(gv[8],  gv[9],  gv[10], gv[11]);
    dst[3] = make_float4(gv[12], gv[13], gv[14], 0.0f);
}

// ---------------------------------------------------------------------------
// Kernel 2: systolic GRU, one batch per wave, one gate per lane.
// Grid: 128 blocks x 128 threads (block = 1 batch; wave0 compute, wave1
// producer staging gi0 chunks into a CT=32 double-buffered LDS ring).
// h-broadcast via readlane->SGPR; dots use SGPR-operand fma trees.
// ---------------------------------------------------------------------------

// producer: stage chunk C into gbuf[C&1]; 128 float4 per chunk, 2 per lane
#define STAGE(C) do {                                                       \
    const int _cb = (C) & 1;                                                \
    float4 _v0, _v1;                                                        \
    {                                                                       \
        const int _t = lane >> 2, _q = lane & 3;                            \
        _v0 = *(const float4*)(gi0 +                                        \
            ((size_t)(((C) * CT + _t) * B_DIM + b)) * 16 + _q * 4);         \
    }                                                                       \
    {                                                                       \
        const int _f = lane + 64, _t = _f >> 2, _q = _f & 3;                \
        _v1 = *(const float4*)(gi0 +                                        \
            ((size_t)(((C) * CT + _t) * B_DIM + b)) * 16 + _q * 4);         \
    }                                                                       \
    *(float4*)&gbuf[_cb][lane >> 2][(lane & 3) * 4] = _v0;                  \
    *(float4*)&gbuf[_cb][(lane + 64) >> 2][((lane + 64) & 3) * 4] = _v1;    \
} while (0)

#define PREF(CB, TL) do { pre = lptr[(CB) * (CT * 16) + (TL) * 16]; } while (0)

// tree dot-5: W per-lane VGPR, S wave-uniform (SGPR) -> 1 SGPR per fma, legal
#define DOT5T(W, S, INIT) ({                                                \
    const float _t0 = (W)[0] * (S)[0];                                      \
    const float _t1 = fmaf((W)[1], (S)[1], (INIT));                         \
    const float _t2 = (W)[2] * (S)[2];                                      \
    const float _t3 = fmaf((W)[3], (S)[3], _t0);                            \
    const float _t4 = fmaf((W)[4], (S)[4], _t1);                            \
    (_t2 + _t3) + _t4; })

#define GSTEP(S, PREFCODE) do {                                             \
    /* candidate dots vs all 3 layer h-vectors (wave-uniform sh) */         \
    const float b0 = DOT5T(wh, sh0, bB);                                    \
    const float b1 = DOT5T(wh, sh1, bB);                                    \
    const float b2 = DOT5T(wh, sh2, bB);                                    \
    const float a1 = DOT5T(wi, sh0, 0.0f);                                  \
    const float a2 = DOT5T(wi, sh1, 0.0f);                                  \
    const float a3 = DOT5T(wi, sh2, 0.0f);                                  \
    const float aB = (row == 0) ? b0 : (row == 1) ? b1 : b2;                \
    const float dA = (row == 1) ? a1 : (row == 2) ? a2 : a3;  /* r0:wi=0 */ \
    const float aA = (bA + pre) + dA;                                       \
    PREFCODE                                                                \
    const float sAv = aA + aB;                                              \
    const float sg  = fast_sigmoid(sAv);                                    \
    const float rn  = dppf<DPP_SHR10>(sg);   /* r_i -> n-lane (g-10) */     \
    const float zn  = dppf<DPP_SHR5>(sg);    /* z_i -> n-lane (g-5)  */     \
    if (lane == 48 && (unsigned)((S) - 3) < (unsigned)T_DIM)                \
        out[((S) - 3) * B_DIM + b] = sAv;    /* projection pre-activation */\
    const float nv = fast_tanh(fmaf(rn, aB, aA));                           \
    const float hu = fmaf(zn, hm - nv, nv);                                 \
    const bool _valid = (unsigned)((S) - row) < (unsigned)T_DIM;            \
    hm = _valid ? hu : hm;                                                  \
    /* broadcast h of all 3 layer-rows via readlane (VALU, no DS pipe) */   \
    _Pragma("unroll") for (int _j = 0; _j < GH; ++_j) {                     \
        sh0[_j] = rlane(hm, 10 + _j);                                       \
        sh1[_j] = rlane(hm, 26 + _j);                                       \
        sh2[_j] = rlane(hm, 42 + _j);                                       \
    }                                                                       \
} while (0)

__global__ __launch_bounds__(128, 1) void gru_kernel(
    const float* __restrict__ gi0,
    const float* __restrict__ whh0, const float* __restrict__ bhh0,
    const float* __restrict__ wih1, const float* __restrict__ whh1,
    const float* __restrict__ bih1, const float* __restrict__ bhh1,
    const float* __restrict__ wih2, const float* __restrict__ whh2,
    const float* __restrict__ bih2, const float* __restrict__ bhh2,
    const float* __restrict__ Wout, const float* __restrict__ bout,
    float* __restrict__ out)
{
    __shared__ float gbuf[2][CT][16];      // 4 KB double-buffered gi0 chunks

    const int tid  = threadIdx.x;
    const int w    = __builtin_amdgcn_readfirstlane(tid >> 6);
    const int lane = tid & 63;
    const int b    = blockIdx.x;           // one batch per block

    if (w == 1) {
        // ---------------- producer wave ----------------
        STAGE(0);
        __syncthreads();                   // chunk 0 visible
        for (int c = 0; c < NCH; ++c) {
            if (c + 1 < NCH) STAGE(c + 1);
            __syncthreads();               // publish chunk c+1; consumer done with c
        }
        return;
    }

    // ---------------- consumer wave ----------------
    const int row = lane >> 4;             // 0..2 = layer, 3 = projection
    const int g   = lane & 15;             // gate (r:0-4, z:5-9, n:10-14)

    // ---- per-lane weights: ONE gate row ----
    float wi[GH], wh[GH];
    float bA = 0.f, bB = 0.f;
#pragma unroll
    for (int j = 0; j < GH; ++j) { wi[j] = 0.f; wh[j] = 0.f; }

    if (row == 0) {
        if (g < 15) {                      // L0: x-side is in gi0 (incl. bih0)
#pragma unroll
            for (int j = 0; j < GH; ++j) wh[j] = whh0[g * GH + j];
            bB = bhh0[g];
        }
    } else if (row < 3) {
        const float* wip = (row == 1) ? wih1 : wih2;
        const float* whp = (row == 1) ? whh1 : whh2;
        const float* bip = (row == 1) ? bih1 : bih2;
        const float* bhp = (row == 1) ? bhh1 : bhh2;
        if (g < 15) {
#pragma unroll
            for (int j = 0; j < GH; ++j) {
                wi[j] = wip[g * GH + j];
                wh[j] = whp[g * GH + j];
            }
            bA = bip[g];
            bB = bhp[g];
        }
    } else if (g == 0) {                   // projection: y = Wout.h2 + bout
#pragma unroll
        for (int j = 0; j < GH; ++j) wi[j] = Wout[j];
        bA = bout[0];
    }

    // ---- pre (gi0) LDS column: row0 lane g -> col g; others -> col 15 (=0)
    const float* lptr = &gbuf[0][0][(row == 0) ? g : 15];

    float sh0[GH] = {0.f, 0.f, 0.f, 0.f, 0.f};
    float sh1[GH] = {0.f, 0.f, 0.f, 0.f, 0.f};
    float sh2[GH] = {0.f, 0.f, 0.f, 0.f, 0.f};
    float hm = 0.f, pre = 0.f;

    __syncthreads();                       // chunk 0 staged
    PREF(0, 0);

    for (int c = 0; c < NCH; ++c) {
        const int cb = c & 1;
#pragma unroll 2
        for (int tl = 0; tl < CT; ++tl) {
            const int s = c * CT + tl;
            GSTEP(s, if (tl + 1 < CT) { PREF(cb, tl + 1); });
        }
        __syncthreads();                   // chunk c done; chunk c+1 published
        if (c + 1 < NCH) { PREF((c + 1) & 1, 0); }
    }

    // drain: 3 wall steps flush the layer pipeline (pre stale but h masked)
    for (int s = T_DIM; s < T_DIM + 3; ++s) {
        GSTEP(s, ;);
    }
}

// ---------------------------------------------------------------------------
extern "C" void kernel_launch(void* const* d_in, const int* in_sizes, int n_in,
                              void* d_out, int out_size, void* d_ws, size_t ws_size,
                              hipStream_t stream)
{
    (void)in_sizes; (void)n_in; (void)out_size; (void)ws_size;

    const float* X    = (const float*)d_in[0];
    const float* W1   = (const float*)d_in[1];
    const float* b1   = (const float*)d_in[2];
    const float* W2   = (const float*)d_in[3];
    const float* b2   = (const float*)d_in[4];
    const float* W3   = (const float*)d_in[5];
    const float* b3   = (const float*)d_in[6];
    const float* wih0 = (const float*)d_in[7];
    const float* whh0 = (const float*)d_in[8];
    const float* bih0 = (const float*)d_in[9];
    const float* bhh0 = (const float*)d_in[10];
    const float* wih1 = (const float*)d_in[11];
    const float* whh1 = (const float*)d_in[12];
    const float* bih1 = (const float*)d_in[13];
    const float* bhh1 = (const float*)d_in[14];
    const float* wih2 = (const float*)d_in[15];
    const float* whh2 = (const float*)d_in[16];
    const float* bih2 = (const float*)d_in[17];
    const float* bhh2 = (const float*)d_in[18];
    const float* Wout = (const float*)d_in[19];
    const float* bout = (const float*)d_in[20];

    ushort* Wp  = (ushort*)d_ws;                       // 400 frags * 1 KB = 400 KB
    float*  gi0 = (float*)((char*)d_ws + 524288);      // (32768, 16) fp32 = 2 MB

    pack_w1_kernel<<<NSTEP, 256, 0, stream>>>(W1, Wp);
    mlp_kernel<<<512, 256, 0, stream>>>(X, Wp, b1, W2, b2, W3, b3, wih0, bih0, gi0);
    gru_kernel<<<128, 128, 0, stream>>>(gi0, whh0, bhh0,
                                        wih1, whh1, bih1, bhh1,
                                        wih2, whh2, bih2, bhh2,
                                        Wout, bout, (float*)d_out);
}

// Round 12
// 128.713 us; speedup vs baseline: 1.1048x; 1.0400x over previous
//
#include <hip/hip_runtime.h>
#include <hip/hip_bf16.h>

// ---------------------------------------------------------------------------
// RnnGruModel: MLP (1600->60->15->10) fused with GRU-layer0 input-gate
// precompute, then 3 stacked GRU layers (H=5) + output projection.
// X@W1^T done in bf16 MFMA with hi/lo split (3 products) -> ~fp32 accuracy.
// R12 mlp: wave-per-M-frag, full-K per wave (no split-K, no cross-wave
// reduction) -> LDS 16.6 KB -> 4 blocks/CU (was 2) -> 2x in-flight loads.
// GRU: R9 exact (verified best): systolic layer pipeline, one batch per
// wave, one gate per lane, bperm broadcast, producer-wave LDS ring.
// Layouts: X (T,B,F) row-major, row r = t*128 + b.  Output (T,1,B): t*128+b.
// ---------------------------------------------------------------------------

#define T_DIM 256
#define B_DIM 128
#define F_DIM 1600
#define H1_DIM 60
#define H2_DIM 15
#define H3_DIM 10
#define GH 5
#define NSTEP 50          // MLP K-steps of 32 (1600/32)
#define CT 32             // GRU LDS chunk: timesteps per buffer
#define NCH (T_DIM / CT)  // 8 chunks

#define DPP_SHR5  0x115   // row_shr:5  (lane i <- lane i-5 within 16-lane row)
#define DPP_SHR10 0x11A   // row_shr:10 (lane i <- lane i-10)

typedef __attribute__((ext_vector_type(8))) short bf16x8;   // MFMA A/B frag (4 VGPRs)
typedef __attribute__((ext_vector_type(4))) float f32x4;    // MFMA C/D frag

__device__ __forceinline__ float fast_tanh(float x) {
    float e = __expf(2.0f * x);
    return 1.0f - __fdividef(2.0f, e + 1.0f);   // safe at +-inf
}
__device__ __forceinline__ float fast_sigmoid(float x) {
    return __fdividef(1.0f, 1.0f + __expf(-x)); // safe at +-inf
}
__device__ __forceinline__ ushort f2bf_rn(float x) {        // round-to-nearest bf16
    uint u = __float_as_uint(x);
    u += 0x7fffu + ((u >> 16) & 1u);
    return (ushort)(u >> 16);
}
template <int CTRL>
__device__ __forceinline__ float dppf(float v) {
    return __int_as_float(
        __builtin_amdgcn_mov_dpp(__float_as_int(v), CTRL, 0xf, 0xf, true));
}
__device__ __forceinline__ float bperm(int addr, float v) {
    return __int_as_float(__builtin_amdgcn_ds_bpermute(addr, __float_as_int(v)));
}

// ---------------------------------------------------------------------------
// Kernel 0: pack W1 (60x1600 fp32, zero-padded to 64 rows) into frag-ordered
// bf16 hi/lo pairs (unchanged, verified).
// ---------------------------------------------------------------------------
__global__ __launch_bounds__(256) void pack_w1_kernel(
    const float* __restrict__ W1, ushort* __restrict__ Wp)
{
    const int s  = blockIdx.x;       // 0..49
    const int t  = threadIdx.x;
    const int nf = t >> 6;
    const int l  = t & 63;
    const int n  = nf * 16 + (l & 15);
    const int g  = l >> 4;

    ushort hi[8], lo[8];
#pragma unroll
    for (int j = 0; j < 8; ++j) {
        const int k = s * 32 + g * 8 + j;
        const float v = (n < H1_DIM) ? W1[n * F_DIM + k] : 0.0f;
        const ushort h = f2bf_rn(v);
        const float hf = __uint_as_float(((uint)h) << 16);
        const float r  = v - hf;                       // exact
        hi[j] = h;
        lo[j] = (ushort)(__float_as_uint(r) >> 16);    // truncate: |err| ~ 2^-17 |v|
    }
    ushort* dst = Wp + ((size_t)(s * 8 + nf * 2)) * 512 + l * 8;
#pragma unroll
    for (int j = 0; j < 8; ++j) dst[j] = hi[j];
#pragma unroll
    for (int j = 0; j < 8; ++j) dst[512 + j] = lo[j];
}

// ---------------------------------------------------------------------------
// Kernel 1: per-row MLP + gi0 precompute, MFMA, full-K-per-wave.
// Grid: 512 blocks x 256 threads. Wave w owns rows row0+w*16..+15 (1 M-frag),
// computes all 4 N-frags over all 50 K-steps (MFMA accumulates K in-register;
// no cross-wave reduction). LDS = one 64x65 fp32 C tile (16.6 KB) -> 4
// blocks/CU occupancy. B-frags re-read per wave (L2-resident, 400 KB).
// Tail: wave 0, lane = row (unchanged, verified).
// ---------------------------------------------------------------------------
__global__ __launch_bounds__(256) void mlp_kernel(
    const float* __restrict__ X,
    const ushort* __restrict__ Wp,
    const float* __restrict__ b1,
    const float* __restrict__ W2, const float* __restrict__ b2,
    const float* __restrict__ W3, const float* __restrict__ b3,
    const float* __restrict__ wih0, const float* __restrict__ bih0,
    float* __restrict__ gi0)
{
    __shared__ float redp[64 * 65];   // 16.25 KB padded C tile

    const int tid  = threadIdx.x;
    const int l    = tid & 63;
    const int w    = __builtin_amdgcn_readfirstlane(tid >> 6);
    const int lm   = l & 15;          // A-row / B-col lane index
    const int g    = l >> 4;          // k-slot group
    const int row0 = blockIdx.x * 64;

    f32x4 acc[4];
#pragma unroll
    for (int nf = 0; nf < 4; ++nf)
        acc[nf] = (f32x4){0.f, 0.f, 0.f, 0.f};

    // this wave's A row pointer (16 rows per wave; lane lm picks the row)
    const float* ap = X + (size_t)(row0 + w * 16 + lm) * F_DIM + g * 8;

    // depth-2 software pipeline on A: load s+1 while converting/MFMAing s
    float4 x0 = *(const float4*)(ap);
    float4 x1 = *(const float4*)(ap + 4);

    for (int s = 0; s < NSTEP; ++s) {
        float4 n0 = make_float4(0.f, 0.f, 0.f, 0.f);
        float4 n1 = n0;
        if (s + 1 < NSTEP) {
            n0 = *(const float4*)(ap + (s + 1) * 32);
            n1 = *(const float4*)(ap + (s + 1) * 32 + 4);
        }
        // B frags: per-lane 16B loads, L2-resident (same addrs across waves)
        bf16x8 bh[4], bl[4];
        const ushort* wp_s = Wp + (size_t)s * 4096 + l * 8;
#pragma unroll
        for (int nf = 0; nf < 4; ++nf) {
            bh[nf] = *(const bf16x8*)(wp_s + (nf * 2 + 0) * 512);
            bl[nf] = *(const bf16x8*)(wp_s + (nf * 2 + 1) * 512);
        }
        // convert A to bf16 hi/lo
        const float xs8[8] = {x0.x, x0.y, x0.z, x0.w, x1.x, x1.y, x1.z, x1.w};
        bf16x8 ah, al;
#pragma unroll
        for (int j = 0; j < 8; ++j) {
            const float v = xs8[j];
            const uint  u = __float_as_uint(v);
            const uint uh = (u + 0x7fffu + ((u >> 16) & 1u)) & 0xffff0000u;
            const float hf = __uint_as_float(uh);
            const float r  = v - hf;               // exact
            ah[j] = (short)(uh >> 16);
            al[j] = (short)(__float_as_uint(r) >> 16);
        }
        // 3-product bf16 emulation of fp32 GEMM
#pragma unroll
        for (int nf = 0; nf < 4; ++nf) {
            f32x4 c = acc[nf];
            c = __builtin_amdgcn_mfma_f32_16x16x32_bf16(al, bh[nf], c, 0, 0, 0);
            c = __builtin_amdgcn_mfma_f32_16x16x32_bf16(ah, bl[nf], c, 0, 0, 0);
            c = __builtin_amdgcn_mfma_f32_16x16x32_bf16(ah, bh[nf], c, 0, 0, 0);
            acc[nf] = c;
        }
        x0 = n0; x1 = n1;
    }

    // C -> LDS (C/D map: col=lane&15, row=(l>>4)*4+q); rows w*16.. for wave w
#pragma unroll
    for (int nf = 0; nf < 4; ++nf)
#pragma unroll
        for (int q = 0; q < 4; ++q)
            redp[(w * 16 + g * 4 + q) * 65 + nf * 16 + lm] = acc[nf][q];
    __syncthreads();
    if (w != 0) return;

    // ---------------- MLP tail + gi0 (wave 0, lane = row) ------------------
    float h1v[H1_DIM];
#pragma unroll
    for (int o = 0; o < H1_DIM; ++o)
        h1v[o] = fast_tanh(redp[l * 65 + o] + b1[o]);

    float h2v[H2_DIM];
#pragma unroll
    for (int j = 0; j < H2_DIM; ++j) {
        float sacc = b2[j];
#pragma unroll
        for (int o = 0; o < H1_DIM; ++o) sacc += W2[j * H1_DIM + o] * h1v[o];
        h2v[j] = fast_tanh(sacc);
    }

    float h3v[H3_DIM];
#pragma unroll
    for (int m = 0; m < H3_DIM; ++m) {
        float sacc = b3[m];
#pragma unroll
        for (int j = 0; j < H2_DIM; ++j) sacc += W3[m * H2_DIM + j] * h2v[j];
        h3v[m] = sacc;
    }

    float gv[15];
#pragma unroll
    for (int q = 0; q < 15; ++q) {
        float sacc = bih0[q];
#pragma unroll
        for (int m = 0; m < H3_DIM; ++m) sacc += wih0[q * H3_DIM + m] * h3v[m];
        gv[q] = sacc;
    }

    const int row = row0 + l;
    float4* dst = (float4*)(gi0 + (size_t)row * 16);
    dst[0] = make_float4(gv[0],  gv[1],  gv[2],  gv[3]);
    dst[1] = make_float4(gv[4],  gv[5],  gv[6],  gv[7]);
    dst[2] = make_float4(gv[8],  gv[9],  gv[10], gv[11]);
    dst[3] = make_float4(gv[12], gv[13], gv[14], 0.0f);
}

// ---------------------------------------------------------------------------
// Kernel 2: systolic GRU, one batch per wave, one gate per lane (R9 exact).
// Grid: 128 blocks x 128 threads (block = 1 batch; wave0 compute, wave1
// producer staging gi0 chunks into a CT=32 double-buffered LDS ring).
// ---------------------------------------------------------------------------

// producer: stage chunk C into gbuf[C&1]; 128 float4 per chunk, 2 per lane
#define STAGE(C) do {                                                       \
    const int _cb = (C) & 1;                                                \
    float4 _v0, _v1;                                                        \
    {                                                                       \
        const int _t = lane >> 2, _q = lane & 3;                            \
        _v0 = *(const float4*)(gi0 +                                        \
            ((size_t)(((C) * CT + _t) * B_DIM + b)) * 16 + _q * 4);         \
    }                                                                       \
    {                                                                       \
        const int _f = lane + 64, _t = _f >> 2, _q = _f & 3;                \
        _v1 = *(const float4*)(gi0 +                                        \
            ((size_t)(((C) * CT + _t) * B_DIM + b)) * 16 + _q * 4);         \
    }                                                                       \
    *(float4*)&gbuf[_cb][lane >> 2][(lane & 3) * 4] = _v0;                  \
    *(float4*)&gbuf[_cb][(lane + 64) >> 2][((lane + 64) & 3) * 4] = _v1;    \
} while (0)

#define PREF(CB, TL) do { pre = lptr[(CB) * (CT * 16) + (TL) * 16]; } while (0)

#define GSTEP(S, PREFCODE) do {                                             \
    /* dots: aA = bA(+gi) + wi.x ; aB = bB + wh.h  (ref-exact order) */     \
    float aA = bA + pre;                                                    \
    _Pragma("unroll") for (int _j = 0; _j < GH; ++_j)                       \
        aA = fmaf(wi[_j], xn[_j], aA);                                      \
    float aB = fmaf(wh[0], hn[0], bB);                                      \
    _Pragma("unroll") for (int _j = 1; _j < GH; ++_j)                       \
        aB = fmaf(wh[_j], hn[_j], aB);                                      \
    PREFCODE                                                                \
    const float sAv = aA + aB;                                              \
    const float sg  = fast_sigmoid(sAv);                                    \
    const float rn  = dppf<DPP_SHR10>(sg);   /* r_i -> n-lane (g-10) */     \
    const float zn  = dppf<DPP_SHR5>(sg);    /* z_i -> n-lane (g-5)  */     \
    if (lane == 48 && (unsigned)((S) - 3) < (unsigned)T_DIM)                \
        out[((S) - 3) * B_DIM + b] = sAv;    /* projection pre-activation */\
    const float nv = fast_tanh(fmaf(rn, aB, aA));                           \
    const float hu = fmaf(zn, hm - nv, nv);                                 \
    const bool _valid = (unsigned)((S) - row) < (unsigned)T_DIM;            \
    hm = _valid ? hu : hm;                                                  \
    /* replicate h (own row) and x (prev row) for next step */              \
    _Pragma("unroll") for (int _j = 0; _j < GH; ++_j) {                     \
        hn[_j] = bperm(a_self[_j], hm);                                     \
        xn[_j] = bperm(a_prev[_j], hm);                                     \
    }                                                                       \
} while (0)

__global__ __launch_bounds__(128, 1) void gru_kernel(
    const float* __restrict__ gi0,
    const float* __restrict__ whh0, const float* __restrict__ bhh0,
    const float* __restrict__ wih1, const float* __restrict__ whh1,
    const float* __restrict__ bih1, const float* __restrict__ bhh1,
    const float* __restrict__ wih2, const float* __restrict__ whh2,
    const float* __restrict__ bih2, const float* __restrict__ bhh2,
    const float* __restrict__ Wout, const float* __restrict__ bout,
    float* __restrict__ out)
{
    __shared__ float gbuf[2][CT][16];      // 4 KB double-buffered gi0 chunks

    const int tid  = threadIdx.x;
    const int w    = __builtin_amdgcn_readfirstlane(tid >> 6);
    const int lane = tid & 63;
    const int b    = blockIdx.x;           // one batch per block

    if (w == 1) {
        // ---------------- producer wave ----------------
        STAGE(0);
        __syncthreads();                   // chunk 0 visible
        for (int c = 0; c < NCH; ++c) {
            if (c + 1 < NCH) STAGE(c + 1);
            __syncthreads();               // publish chunk c+1; consumer done with c
        }
        return;
    }

    // ---------------- consumer wave ----------------
    const int row = lane >> 4;             // 0..2 = layer, 3 = projection
    const int g   = lane & 15;             // gate (r:0-4, z:5-9, n:10-14)

    // ---- per-lane weights: ONE gate row ----
    float wi[GH], wh[GH];
    float bA = 0.f, bB = 0.f;
#pragma unroll
    for (int j = 0; j < GH; ++j) { wi[j] = 0.f; wh[j] = 0.f; }

    if (row == 0) {
        if (g < 15) {                      // L0: x-side is in gi0 (incl. bih0)
#pragma unroll
            for (int j = 0; j < GH; ++j) wh[j] = whh0[g * GH + j];
            bB = bhh0[g];
        }
    } else if (row < 3) {
        const float* wip = (row == 1) ? wih1 : wih2;
        const float* whp = (row == 1) ? whh1 : whh2;
        const float* bip = (row == 1) ? bih1 : bih2;
        const float* bhp = (row == 1) ? bhh1 : bhh2;
        if (g < 15) {
#pragma unroll
            for (int j = 0; j < GH; ++j) {
                wi[j] = wip[g * GH + j];
                wh[j] = whp[g * GH + j];
            }
            bA = bip[g];
            bB = bhp[g];
        }
    } else if (g == 0) {                   // projection: y = Wout.h2 + bout
#pragma unroll
        for (int j = 0; j < GH; ++j) wi[j] = Wout[j];
        bA = bout[0];
    }

    // ---- bpermute addresses (constant): n-lanes of own / previous row ----
    int a_self[GH], a_prev[GH];
    const int sbase = row * 16;
    const int pbase = ((row + 3) & 3) * 16;    // row-1 mod 4 (row0 wraps; x*0)
#pragma unroll
    for (int j = 0; j < GH; ++j) {
        a_self[j] = (sbase + 10 + j) << 2;
        a_prev[j] = (pbase + 10 + j) << 2;
    }

    // ---- pre (gi0) LDS column: row0 lane g -> col g; others -> col 15 (=0)
    const float* lptr = &gbuf[0][0][(row == 0) ? g : 15];

    float hn[GH] = {0.f, 0.f, 0.f, 0.f, 0.f};
    float xn[GH] = {0.f, 0.f, 0.f, 0.f, 0.f};
    float hm = 0.f, pre = 0.f;

    __syncthreads();                       // chunk 0 staged
    PREF(0, 0);

    for (int c = 0; c < NCH; ++c) {
        const int cb = c & 1;
#pragma unroll 2
        for (int tl = 0; tl < CT; ++tl) {
            const int s = c * CT + tl;
            GSTEP(s, if (tl + 1 < CT) { PREF(cb, tl + 1); });
        }
        __syncthreads();                   // chunk c done; chunk c+1 published
        if (c + 1 < NCH) { PREF((c + 1) & 1, 0); }
    }

    // drain: 3 wall steps flush the layer pipeline (pre stale but h masked)
    for (int s = T_DIM; s < T_DIM + 3; ++s) {
        GSTEP(s, ;);
    }
}

// ---------------------------------------------------------------------------
extern "C" void kernel_launch(void* const* d_in, const int* in_sizes, int n_in,
                              void* d_out, int out_size, void* d_ws, size_t ws_size,
                              hipStream_t stream)
{
    (void)in_sizes; (void)n_in; (void)out_size; (void)ws_size;

    const float* X    = (const float*)d_in[0];
    const float* W1   = (const float*)d_in[1];
    const float* b1   = (const float*)d_in[2];
    const float* W2   = (const float*)d_in[3];
    const float* b2   = (const float*)d_in[4];
    const float* W3   = (const float*)d_in[5];
    const float* b3   = (const float*)d_in[6];
    const float* wih0 = (const float*)d_in[7];
    const float* whh0 = (const float*)d_in[8];
    const float* bih0 = (const float*)d_in[9];
    const float* bhh0 = (const float*)d_in[10];
    const float* wih1 = (const float*)d_in[11];
    const float* whh1 = (const float*)d_in[12];
    const float* bih1 = (const float*)d_in[13];
    const float* bhh1 = (const float*)d_in[14];
    const float* wih2 = (const float*)d_in[15];
    const float* whh2 = (const float*)d_in[16];
    const float* bih2 = (const float*)d_in[17];
    const float* bhh2 = (const float*)d_in[18];
    const float* Wout = (const float*)d_in[19];
    const float* bout = (const float*)d_in[20];

    ushort* Wp  = (ushort*)d_ws;                       // 400 frags * 1 KB = 400 KB
    float*  gi0 = (float*)((char*)d_ws + 524288);      // (32768, 16) fp32 = 2 MB

    pack_w1_kernel<<<NSTEP, 256, 0, stream>>>(W1, Wp);
    mlp_kernel<<<512, 256, 0, stream>>>(X, Wp, b1, W2, b2, W3, b3, wih0, bih0, gi0);
    gru_kernel<<<128, 128, 0, stream>>>(gi0, whh0, bhh0,
                                        wih1, whh1, bih1, bhh1,
                                        wih2, whh2, bih2, bhh2,
                                        Wout, bout, (float*)d_out);
}

// Round 13
// 112.338 us; speedup vs baseline: 1.2659x; 1.1458x over previous
//
#include <hip/hip_runtime.h>
#include <hip/hip_bf16.h>

// ---------------------------------------------------------------------------
// RnnGruModel: MLP (1600->60->15->10) fused with GRU-layer0 input-gate
// precompute, then 3 stacked GRU layers (H=5) + output projection.
// X@W1^T done in bf16 MFMA with hi/lo split (3 products) -> ~fp32 accuracy.
// R13 mlp: split-K (verified R3 structure) with 32-row tiles and 1024
// blocks -> 4096 waves = 16 waves/CU grid cap (R9/R12 were capped at 8).
// Each wave: one 400-float K-quarter, 12-13 K-steps (the proven config).
// GRU: R9 exact (verified best): systolic layer pipeline, one batch per
// wave, one gate per lane, bperm broadcast, producer-wave LDS ring.
// Layouts: X (T,B,F) row-major, row r = t*128 + b.  Output (T,1,B): t*128+b.
// ---------------------------------------------------------------------------

#define T_DIM 256
#define B_DIM 128
#define F_DIM 1600
#define H1_DIM 60
#define H2_DIM 15
#define H3_DIM 10
#define GH 5
#define NSTEP 50          // MLP K-steps of 32 (1600/32)
#define CT 32             // GRU LDS chunk: timesteps per buffer
#define NCH (T_DIM / CT)  // 8 chunks

#define DPP_SHR5  0x115   // row_shr:5  (lane i <- lane i-5 within 16-lane row)
#define DPP_SHR10 0x11A   // row_shr:10 (lane i <- lane i-10)

typedef __attribute__((ext_vector_type(8))) short bf16x8;   // MFMA A/B frag (4 VGPRs)
typedef __attribute__((ext_vector_type(4))) float f32x4;    // MFMA C/D frag

__device__ __forceinline__ float fast_tanh(float x) {
    float e = __expf(2.0f * x);
    return 1.0f - __fdividef(2.0f, e + 1.0f);   // safe at +-inf
}
__device__ __forceinline__ float fast_sigmoid(float x) {
    return __fdividef(1.0f, 1.0f + __expf(-x)); // safe at +-inf
}
__device__ __forceinline__ ushort f2bf_rn(float x) {        // round-to-nearest bf16
    uint u = __float_as_uint(x);
    u += 0x7fffu + ((u >> 16) & 1u);
    return (ushort)(u >> 16);
}
template <int CTRL>
__device__ __forceinline__ float dppf(float v) {
    return __int_as_float(
        __builtin_amdgcn_mov_dpp(__float_as_int(v), CTRL, 0xf, 0xf, true));
}
__device__ __forceinline__ float bperm(int addr, float v) {
    return __int_as_float(__builtin_amdgcn_ds_bpermute(addr, __float_as_int(v)));
}

// ---------------------------------------------------------------------------
// Kernel 0: pack W1 (60x1600 fp32, zero-padded to 64 rows) into frag-ordered
// bf16 hi/lo pairs (unchanged, verified).
// ---------------------------------------------------------------------------
__global__ __launch_bounds__(256) void pack_w1_kernel(
    const float* __restrict__ W1, ushort* __restrict__ Wp)
{
    const int s  = blockIdx.x;       // 0..49
    const int t  = threadIdx.x;
    const int nf = t >> 6;
    const int l  = t & 63;
    const int n  = nf * 16 + (l & 15);
    const int g  = l >> 4;

    ushort hi[8], lo[8];
#pragma unroll
    for (int j = 0; j < 8; ++j) {
        const int k = s * 32 + g * 8 + j;
        const float v = (n < H1_DIM) ? W1[n * F_DIM + k] : 0.0f;
        const ushort h = f2bf_rn(v);
        const float hf = __uint_as_float(((uint)h) << 16);
        const float r  = v - hf;                       // exact
        hi[j] = h;
        lo[j] = (ushort)(__float_as_uint(r) >> 16);    // truncate: |err| ~ 2^-17 |v|
    }
    ushort* dst = Wp + ((size_t)(s * 8 + nf * 2)) * 512 + l * 8;
#pragma unroll
    for (int j = 0; j < 8; ++j) dst[j] = hi[j];
#pragma unroll
    for (int j = 0; j < 8; ++j) dst[512 + j] = lo[j];
}

// ---------------------------------------------------------------------------
// Kernel 1: per-row MLP + gi0 precompute, MFMA split-K, 32-row tiles.
// Grid: 1024 blocks x 256 threads. Block owns 32 rows (2 M-frags); the 4
// waves split the 50 K-steps (12/13/12/13) and all compute the same 32x64
// C-tile; partials reduced through 32 KB LDS. fp32 tail on wave 0 (l<32).
// ---------------------------------------------------------------------------
__global__ __launch_bounds__(256) void mlp_kernel(
    const float* __restrict__ X,
    const ushort* __restrict__ Wp,
    const float* __restrict__ b1,
    const float* __restrict__ W2, const float* __restrict__ b2,
    const float* __restrict__ W3, const float* __restrict__ b3,
    const float* __restrict__ wih0, const float* __restrict__ bih0,
    float* __restrict__ gi0)
{
    __shared__ float red[4][2048];    // 32 KB: per-wave 32x64 C partials

    const int tid  = threadIdx.x;
    const int l    = tid & 63;
    const int w    = __builtin_amdgcn_readfirstlane(tid >> 6);
    const int lm   = l & 15;          // A-row / B-col lane index
    const int g    = l >> 4;          // k-slot group
    const int row0 = blockIdx.x * 32;

    f32x4 acc[2][4];
#pragma unroll
    for (int mf = 0; mf < 2; ++mf)
#pragma unroll
        for (int nf = 0; nf < 4; ++nf)
            acc[mf][nf] = (f32x4){0.f, 0.f, 0.f, 0.f};

    const int s0 = (w * NSTEP) >> 2;        // 0,12,25,37
    const int s1 = ((w + 1) * NSTEP) >> 2;  // 12,25,37,50

    // depth-2 software pipeline on A (2 M-frags x 8 floats per lane)
    float4 x0[2], x1[2];
#pragma unroll
    for (int mf = 0; mf < 2; ++mf) {
        const float* ap = X + (size_t)(row0 + mf * 16 + lm) * F_DIM + s0 * 32 + g * 8;
        x0[mf] = *(const float4*)ap;
        x1[mf] = *(const float4*)(ap + 4);
    }

    for (int s = s0; s < s1; ++s) {
        float4 n0[2], n1[2];
#pragma unroll
        for (int mf = 0; mf < 2; ++mf) {
            n0[mf] = make_float4(0.f, 0.f, 0.f, 0.f);
            n1[mf] = n0[mf];
        }
        if (s + 1 < s1) {
#pragma unroll
            for (int mf = 0; mf < 2; ++mf) {
                const float* ap = X + (size_t)(row0 + mf * 16 + lm) * F_DIM
                                + (s + 1) * 32 + g * 8;
                n0[mf] = *(const float4*)ap;
                n1[mf] = *(const float4*)(ap + 4);
            }
        }
        // B frags: per-lane 16B loads, L2-resident (400 KB total)
        bf16x8 bh[4], bl[4];
        const ushort* wp_s = Wp + (size_t)s * 4096 + l * 8;
#pragma unroll
        for (int nf = 0; nf < 4; ++nf) {
            bh[nf] = *(const bf16x8*)(wp_s + (nf * 2 + 0) * 512);
            bl[nf] = *(const bf16x8*)(wp_s + (nf * 2 + 1) * 512);
        }
        // convert A to bf16 hi/lo, then 3-product MFMA
#pragma unroll
        for (int mf = 0; mf < 2; ++mf) {
            const float xs8[8] = {x0[mf].x, x0[mf].y, x0[mf].z, x0[mf].w,
                                  x1[mf].x, x1[mf].y, x1[mf].z, x1[mf].w};
            bf16x8 ah, al;
#pragma unroll
            for (int j = 0; j < 8; ++j) {
                const float v = xs8[j];
                const uint  u = __float_as_uint(v);
                const uint uh = (u + 0x7fffu + ((u >> 16) & 1u)) & 0xffff0000u;
                const float hf = __uint_as_float(uh);
                const float r  = v - hf;               // exact
                ah[j] = (short)(uh >> 16);
                al[j] = (short)(__float_as_uint(r) >> 16);
            }
#pragma unroll
            for (int nf = 0; nf < 4; ++nf) {
                f32x4 c = acc[mf][nf];
                c = __builtin_amdgcn_mfma_f32_16x16x32_bf16(al, bh[nf], c, 0, 0, 0);
                c = __builtin_amdgcn_mfma_f32_16x16x32_bf16(ah, bl[nf], c, 0, 0, 0);
                c = __builtin_amdgcn_mfma_f32_16x16x32_bf16(ah, bh[nf], c, 0, 0, 0);
                acc[mf][nf] = c;
            }
        }
#pragma unroll
        for (int mf = 0; mf < 2; ++mf) { x0[mf] = n0[mf]; x1[mf] = n1[mf]; }
    }

    // -------- per-wave C partials -> LDS (C/D map: col=lane&15, row=g*4+q)
    float* myred = &red[w][0];
#pragma unroll
    for (int mf = 0; mf < 2; ++mf)
#pragma unroll
        for (int nf = 0; nf < 4; ++nf)
#pragma unroll
            for (int q = 0; q < 4; ++q)
                myred[(mf * 16 + g * 4 + q) * 64 + nf * 16 + lm] = acc[mf][nf][q];
    __syncthreads();

    // -------- cross-wave reduce (coalesced), write padded 32x65 ------------
    float rsum[8];
#pragma unroll
    for (int i = 0; i < 8; ++i) {
        const int p = tid + 256 * i;
        rsum[i] = red[0][p] + red[1][p] + red[2][p] + red[3][p];
    }
    __syncthreads();
    float* redp = &red[2][0];              // 32 x 65 = 2080 floats (slots 2-3)
#pragma unroll
    for (int i = 0; i < 8; ++i) {
        const int p = tid + 256 * i;
        redp[(p >> 6) * 65 + (p & 63)] = rsum[i];
    }
    __syncthreads();
    if (w != 0 || l >= 32) return;

    // ---------------- MLP tail + gi0 (wave 0, lane = row, 32 rows) ---------
    float h1v[H1_DIM];
#pragma unroll
    for (int o = 0; o < H1_DIM; ++o)
        h1v[o] = fast_tanh(redp[l * 65 + o] + b1[o]);

    float h2v[H2_DIM];
#pragma unroll
    for (int j = 0; j < H2_DIM; ++j) {
        float sacc = b2[j];
#pragma unroll
        for (int o = 0; o < H1_DIM; ++o) sacc += W2[j * H1_DIM + o] * h1v[o];
        h2v[j] = fast_tanh(sacc);
    }

    float h3v[H3_DIM];
#pragma unroll
    for (int m = 0; m < H3_DIM; ++m) {
        float sacc = b3[m];
#pragma unroll
        for (int j = 0; j < H2_DIM; ++j) sacc += W3[m * H2_DIM + j] * h2v[j];
        h3v[m] = sacc;
    }

    float gv[15];
#pragma unroll
    for (int q = 0; q < 15; ++q) {
        float sacc = bih0[q];
#pragma unroll
        for (int m = 0; m < H3_DIM; ++m) sacc += wih0[q * H3_DIM + m] * h3v[m];
        gv[q] = sacc;
    }

    const int row = row0 + l;
    float4* dst = (float4*)(gi0 + (size_t)row * 16);
    dst[0] = make_float4(gv[0],  gv[1],  gv[2],  gv[3]);
    dst[1] = make_float4(gv[4],  gv[5],  gv[6],  gv[7]);
    dst[2] = make_float4(gv[8],  gv[9],  gv[10], gv[11]);
    dst[3] = make_float4(gv[12], gv[13], gv[14], 0.0f);
}

// ---------------------------------------------------------------------------
// Kernel 2: systolic GRU, one batch per wave, one gate per lane (R9 exact).
// Grid: 128 blocks x 128 threads (block = 1 batch; wave0 compute, wave1
// producer staging gi0 chunks into a CT=32 double-buffered LDS ring).
// ---------------------------------------------------------------------------

// producer: stage chunk C into gbuf[C&1]; 128 float4 per chunk, 2 per lane
#define STAGE(C) do {                                                       \
    const int _cb = (C) & 1;                                                \
    float4 _v0, _v1;                                                        \
    {                                                                       \
        const int _t = lane >> 2, _q = lane & 3;                            \
        _v0 = *(const float4*)(gi0 +                                        \
            ((size_t)(((C) * CT + _t) * B_DIM + b)) * 16 + _q * 4);         \
    }                                                                       \
    {                                                                       \
        const int _f = lane + 64, _t = _f >> 2, _q = _f & 3;                \
        _v1 = *(const float4*)(gi0 +                                        \
            ((size_t)(((C) * CT + _t) * B_DIM + b)) * 16 + _q * 4);         \
    }                                                                       \
    *(float4*)&gbuf[_cb][lane >> 2][(lane & 3) * 4] = _v0;                  \
    *(float4*)&gbuf[_cb][(lane + 64) >> 2][((lane + 64) & 3) * 4] = _v1;    \
} while (0)

#define PREF(CB, TL) do { pre = lptr[(CB) * (CT * 16) + (TL) * 16]; } while (0)

#define GSTEP(S, PREFCODE) do {                                             \
    /* dots: aA = bA(+gi) + wi.x ; aB = bB + wh.h  (ref-exact order) */     \
    float aA = bA + pre;                                                    \
    _Pragma("unroll") for (int _j = 0; _j < GH; ++_j)                       \
        aA = fmaf(wi[_j], xn[_j], aA);                                      \
    float aB = fmaf(wh[0], hn[0], bB);                                      \
    _Pragma("unroll") for (int _j = 1; _j < GH; ++_j)                       \
        aB = fmaf(wh[_j], hn[_j], aB);                                      \
    PREFCODE                                                                \
    const float sAv = aA + aB;                                              \
    const float sg  = fast_sigmoid(sAv);                                    \
    const float rn  = dppf<DPP_SHR10>(sg);   /* r_i -> n-lane (g-10) */     \
    const float zn  = dppf<DPP_SHR5>(sg);    /* z_i -> n-lane (g-5)  */     \
    if (lane == 48 && (unsigned)((S) - 3) < (unsigned)T_DIM)                \
        out[((S) - 3) * B_DIM + b] = sAv;    /* projection pre-activation */\
    const float nv = fast_tanh(fmaf(rn, aB, aA));                           \
    const float hu = fmaf(zn, hm - nv, nv);                                 \
    const bool _valid = (unsigned)((S) - row) < (unsigned)T_DIM;            \
    hm = _valid ? hu : hm;                                                  \
    /* replicate h (own row) and x (prev row) for next step */              \
    _Pragma("unroll") for (int _j = 0; _j < GH; ++_j) {                     \
        hn[_j] = bperm(a_self[_j], hm);                                     \
        xn[_j] = bperm(a_prev[_j], hm);                                     \
    }                                                                       \
} while (0)

__global__ __launch_bounds__(128, 1) void gru_kernel(
    const float* __restrict__ gi0,
    const float* __restrict__ whh0, const float* __restrict__ bhh0,
    const float* __restrict__ wih1, const float* __restrict__ whh1,
    const float* __restrict__ bih1, const float* __restrict__ bhh1,
    const float* __restrict__ wih2, const float* __restrict__ whh2,
    const float* __restrict__ bih2, const float* __restrict__ bhh2,
    const float* __restrict__ Wout, const float* __restrict__ bout,
    float* __restrict__ out)
{
    __shared__ float gbuf[2][CT][16];      // 4 KB double-buffered gi0 chunks

    const int tid  = threadIdx.x;
    const int w    = __builtin_amdgcn_readfirstlane(tid >> 6);
    const int lane = tid & 63;
    const int b    = blockIdx.x;           // one batch per block

    if (w == 1) {
        // ---------------- producer wave ----------------
        STAGE(0);
        __syncthreads();                   // chunk 0 visible
        for (int c = 0; c < NCH; ++c) {
            if (c + 1 < NCH) STAGE(c + 1);
            __syncthreads();               // publish chunk c+1; consumer done with c
        }
        return;
    }

    // ---------------- consumer wave ----------------
    const int row = lane >> 4;             // 0..2 = layer, 3 = projection
    const int g   = lane & 15;             // gate (r:0-4, z:5-9, n:10-14)

    // ---- per-lane weights: ONE gate row ----
    float wi[GH], wh[GH];
    float bA = 0.f, bB = 0.f;
#pragma unroll
    for (int j = 0; j < GH; ++j) { wi[j] = 0.f; wh[j] = 0.f; }

    if (row == 0) {
        if (g < 15) {                      // L0: x-side is in gi0 (incl. bih0)
#pragma unroll
            for (int j = 0; j < GH; ++j) wh[j] = whh0[g * GH + j];
            bB = bhh0[g];
        }
    } else if (row < 3) {
        const float* wip = (row == 1) ? wih1 : wih2;
        const float* whp = (row == 1) ? whh1 : whh2;
        const float* bip = (row == 1) ? bih1 : bih2;
        const float* bhp = (row == 1) ? bhh1 : bhh2;
        if (g < 15) {
#pragma unroll
            for (int j = 0; j < GH; ++j) {
                wi[j] = wip[g * GH + j];
                wh[j] = whp[g * GH + j];
            }
            bA = bip[g];
            bB = bhp[g];
        }
    } else if (g == 0) {                   // projection: y = Wout.h2 + bout
#pragma unroll
        for (int j = 0; j < GH; ++j) wi[j] = Wout[j];
        bA = bout[0];
    }

    // ---- bpermute addresses (constant): n-lanes of own / previous row ----
    int a_self[GH], a_prev[GH];
    const int sbase = row * 16;
    const int pbase = ((row + 3) & 3) * 16;    // row-1 mod 4 (row0 wraps; x*0)
#pragma unroll
    for (int j = 0; j < GH; ++j) {
        a_self[j] = (sbase + 10 + j) << 2;
        a_prev[j] = (pbase + 10 + j) << 2;
    }

    // ---- pre (gi0) LDS column: row0 lane g -> col g; others -> col 15 (=0)
    const float* lptr = &gbuf[0][0][(row == 0) ? g : 15];

    float hn[GH] = {0.f, 0.f, 0.f, 0.f, 0.f};
    float xn[GH] = {0.f, 0.f, 0.f, 0.f, 0.f};
    float hm = 0.f, pre = 0.f;

    __syncthreads();                       // chunk 0 staged
    PREF(0, 0);

    for (int c = 0; c < NCH; ++c) {
        const int cb = c & 1;
#pragma unroll 2
        for (int tl = 0; tl < CT; ++tl) {
            const int s = c * CT + tl;
            GSTEP(s, if (tl + 1 < CT) { PREF(cb, tl + 1); });
        }
        __syncthreads();                   // chunk c done; chunk c+1 published
        if (c + 1 < NCH) { PREF((c + 1) & 1, 0); }
    }

    // drain: 3 wall steps flush the layer pipeline (pre stale but h masked)
    for (int s = T_DIM; s < T_DIM + 3; ++s) {
        GSTEP(s, ;);
    }
}

// ---------------------------------------------------------------------------
extern "C" void kernel_launch(void* const* d_in, const int* in_sizes, int n_in,
                              void* d_out, int out_size, void* d_ws, size_t ws_size,
                              hipStream_t stream)
{
    (void)in_sizes; (void)n_in; (void)out_size; (void)ws_size;

    const float* X    = (const float*)d_in[0];
    const float* W1   = (const float*)d_in[1];
    const float* b1   = (const float*)d_in[2];
    const float* W2   = (const float*)d_in[3];
    const float* b2   = (const float*)d_in[4];
    const float* W3   = (const float*)d_in[5];
    const float* b3   = (const float*)d_in[6];
    const float* wih0 = (const float*)d_in[7];
    const float* whh0 = (const float*)d_in[8];
    const float* bih0 = (const float*)d_in[9];
    const float* bhh0 = (const float*)d_in[10];
    const float* wih1 = (const float*)d_in[11];
    const float* whh1 = (const float*)d_in[12];
    const float* bih1 = (const float*)d_in[13];
    const float* bhh1 = (const float*)d_in[14];
    const float* wih2 = (const float*)d_in[15];
    const float* whh2 = (const float*)d_in[16];
    const float* bih2 = (const float*)d_in[17];
    const float* bhh2 = (const float*)d_in[18];
    const float* Wout = (const float*)d_in[19];
    const float* bout = (const float*)d_in[20];

    ushort* Wp  = (ushort*)d_ws;                       // 400 frags * 1 KB = 400 KB
    float*  gi0 = (float*)((char*)d_ws + 524288);      // (32768, 16) fp32 = 2 MB

    pack_w1_kernel<<<NSTEP, 256, 0, stream>>>(W1, Wp);
    mlp_kernel<<<1024, 256, 0, stream>>>(X, Wp, b1, W2, b2, W3, b3, wih0, bih0, gi0);
    gru_kernel<<<128, 128, 0, stream>>>(gi0, whh0, bhh0,
                                        wih1, whh1, bih1, bhh1,
                                        wih2, whh2, bih2, bhh2,
                                        Wout, bout, (float*)d_out);
}